// Round 3
// baseline (170.058 us; speedup 1.0000x reference)
//
#include <hip/hip_runtime.h>
#include <hip/hip_bf16.h>
#include <stdint.h>

#define H_ 128
#define THREADS 256
#define EDGES_PER_BLOCK 128   // 4 waves x 32 edges
#define NBUCKET 4096

typedef __bf16 bf16x8 __attribute__((ext_vector_type(8)));
typedef float  f32x4  __attribute__((ext_vector_type(4)));

// ---------------------------------------------------------------------------
// wfrag layout (bf16 MFMA B-fragment order), idx = ks*4096 + nt*512 + lane*8 + j
//   k = ks*32 + (lane>>4)*8 + j   (K index into [zu|za] concat, 0..255)
//   n = nt*16 + (lane&15)         (output channel, 0..127)
// ---------------------------------------------------------------------------

__device__ inline bf16x8 pack8(float4 a, float4 b) {
    bf16x8 v;
    v[0] = (__bf16)a.x; v[1] = (__bf16)a.y; v[2] = (__bf16)a.z; v[3] = (__bf16)a.w;
    v[4] = (__bf16)b.x; v[5] = (__bf16)b.y; v[6] = (__bf16)b.z; v[7] = (__bf16)b.w;
    return v;
}

// Combined prep: W1 -> bf16 fragment order (first 128 blocks), z_anime -> bf16.
__global__ void prep_kernel(const float* __restrict__ W1,
                            const float* __restrict__ za,
                            __bf16* __restrict__ wfrag,
                            __bf16* __restrict__ za_bf,
                            int nza) {
    int t = blockIdx.x * 256 + threadIdx.x;
    if (t < 32768) {
        int j  = t & 7;
        int ln = (t >> 3) & 63;
        int nt = (t >> 9) & 7;
        int ks = (t >> 12) & 7;
        int k  = ks * 32 + ((ln >> 4) << 3) + j;
        int n  = nt * 16 + (ln & 15);
        wfrag[t] = (__bf16)W1[k * H_ + n];
    } else {
        long i = (long)(t - 32768) * 8;
        if (i < nza) {
            float4 a = *(const float4*)(za + i);
            float4 b = *(const float4*)(za + i + 4);
            *(bf16x8*)(za_bf + i) = pack8(a, b);
        }
    }
}

__global__ void hist_kernel(const int* __restrict__ row, int* __restrict__ hist,
                            int E, int shift) {
    int i = blockIdx.x * blockDim.x + threadIdx.x;
    int stride = gridDim.x * blockDim.x;
    for (; i < E; i += stride)
        atomicAdd(&hist[row[i] >> shift], 1);
}

// Exclusive scan of NBUCKET ints in-place. One block of 1024 threads.
__global__ __launch_bounds__(1024)
void scan_kernel(int* __restrict__ h) {
    __shared__ int wsum[16];
    int tid = threadIdx.x;
    int4 v = *(int4*)(h + tid * 4);
    int s = v.x + v.y + v.z + v.w;
    int lane = tid & 63, wv = tid >> 6;
    int inc = s;
    #pragma unroll
    for (int off = 1; off < 64; off <<= 1) {
        int t = __shfl_up(inc, off, 64);
        if (lane >= off) inc += t;
    }
    if (lane == 63) wsum[wv] = inc;
    __syncthreads();
    if (wv == 0) {
        int ws = (lane < 16) ? wsum[lane] : 0;
        #pragma unroll
        for (int off = 1; off < 16; off <<= 1) {
            int t = __shfl_up(ws, off, 64);
            if (lane >= off) ws += t;
        }
        if (lane < 16) wsum[lane] = ws;   // inclusive wave sums
    }
    __syncthreads();
    int waveoff = (wv > 0) ? wsum[wv - 1] : 0;
    int excl = waveoff + inc - s;
    int4 o;
    o.x = excl; o.y = excl + v.x; o.z = o.y + v.y; o.w = o.z + v.z;
    *(int4*)(h + tid * 4) = o;
}

__global__ void scatter_kernel(const int* __restrict__ row, const int* __restrict__ col,
                               int* __restrict__ hist,
                               int* __restrict__ rowp, int* __restrict__ colp,
                               int* __restrict__ perm, int E, int shift) {
    int i = blockIdx.x * blockDim.x + threadIdx.x;
    int stride = gridDim.x * blockDim.x;
    for (; i < E; i += stride) {
        int r = row[i], c = col[i];
        int pos = atomicAdd(&hist[r >> shift], 1);
        rowp[pos] = r;
        colp[pos] = c;
        perm[pos] = i;
    }
}

__global__ __launch_bounds__(THREADS, 3)
void edge_decoder_kernel(const float* __restrict__ z_user,
                         const float* __restrict__ z_anime,
                         const int*   __restrict__ rowp,
                         const int*   __restrict__ colp,
                         const int*   __restrict__ perm,   // null -> direct store
                         const float* __restrict__ W1,
                         const float* __restrict__ b1,
                         const float* __restrict__ W2,
                         const float* __restrict__ b2,
                         const __bf16* __restrict__ wfrag,
                         const __bf16* __restrict__ za_bf,
                         int use_ws,
                         float* __restrict__ out,
                         int E) {
    // One K-phase of B fragments: [ks 0..3][nt][lane] of 8 bf16 = 32 KiB
    __shared__ bf16x8 Bf[4][8][64];

    const int tid  = threadIdx.x;
    const int lane = tid & 63;
    const int wv   = tid >> 6;
    const int g    = lane >> 4;   // k-group within 32-wide K-step
    const int m    = lane & 15;   // edge-within-Mtile (A); channel-within-Ntile (C)
    const int base = blockIdx.x * EDGES_PER_BLOCK + wv * 32;

    int e0 = base + m;        int e0c = e0 < E ? e0 : 0;
    int e1 = base + 16 + m;   int e1c = e1 < E ? e1 : 0;
    const int r0 = rowp[e0c], c0 = colp[e0c];
    const int r1 = rowp[e1c], c1 = colp[e1c];

    // ---- gather zu (fp32 -> bf16 in registers), phase-0 A operands ----
    bf16x8 Au0[4], Au1[4];
    {
        const float* zu0 = z_user + (size_t)r0 * H_ + g * 8;
        const float* zu1 = z_user + (size_t)r1 * H_ + g * 8;
        #pragma unroll
        for (int ks = 0; ks < 4; ++ks) {
            float4 x0 = *(const float4*)(zu0 + ks * 32);
            float4 y0 = *(const float4*)(zu0 + ks * 32 + 4);
            float4 x1 = *(const float4*)(zu1 + ks * 32);
            float4 y1 = *(const float4*)(zu1 + ks * 32 + 4);
            Au0[ks] = pack8(x0, y0);
            Au1[ks] = pack8(x1, y1);
        }
    }

    // ---- stage W1 phase 0 (ks 0..3) ----
    if (use_ws) {
        const int4* src = (const int4*)wfrag;       // phase 0 at offset 0
        int4*       dst = (int4*)&Bf[0][0][0];
        #pragma unroll
        for (int i = 0; i < 8; ++i)
            dst[tid + i * THREADS] = src[tid + i * THREADS];
    } else {
        __bf16* d = (__bf16*)&Bf[0][0][0];
        for (int idx = tid; idx < H_ * H_; idx += THREADS) {
            int k = idx >> 7, n = idx & 127;
            int ks = k >> 5, gg = (k >> 3) & 3, j = k & 7;
            int nt = n >> 4, ln = (gg << 4) | (n & 15);
            d[ks * 4096 + nt * 512 + ln * 8 + j] = (__bf16)W1[k * H_ + n];
        }
    }
    __syncthreads();

    f32x4 acc0[8], acc1[8];
    #pragma unroll
    for (int nt = 0; nt < 8; ++nt) {
        acc0[nt] = (f32x4){0.f, 0.f, 0.f, 0.f};
        acc1[nt] = (f32x4){0.f, 0.f, 0.f, 0.f};
    }

    // ---- phase 0 MFMAs: zu @ W1[:128] ----
    #pragma unroll
    for (int nt = 0; nt < 8; ++nt) {
        #pragma unroll
        for (int ks = 0; ks < 4; ++ks) {
            bf16x8 b = Bf[ks][nt][lane];
            acc0[nt] = __builtin_amdgcn_mfma_f32_16x16x32_bf16(Au0[ks], b, acc0[nt], 0, 0, 0);
            acc1[nt] = __builtin_amdgcn_mfma_f32_16x16x32_bf16(Au1[ks], b, acc1[nt], 0, 0, 0);
        }
    }

    // ---- issue za loads (overlap with barrier + phase-1 staging) ----
    bf16x8 Aa0[4], Aa1[4];
    if (use_ws) {
        const __bf16* za0 = za_bf + (size_t)c0 * H_ + g * 8;
        const __bf16* za1 = za_bf + (size_t)c1 * H_ + g * 8;
        #pragma unroll
        for (int ks = 0; ks < 4; ++ks) {
            Aa0[ks] = *(const bf16x8*)(za0 + ks * 32);
            Aa1[ks] = *(const bf16x8*)(za1 + ks * 32);
        }
    } else {
        const float* za0 = z_anime + (size_t)c0 * H_ + g * 8;
        const float* za1 = z_anime + (size_t)c1 * H_ + g * 8;
        #pragma unroll
        for (int ks = 0; ks < 4; ++ks) {
            float4 x0 = *(const float4*)(za0 + ks * 32);
            float4 y0 = *(const float4*)(za0 + ks * 32 + 4);
            float4 x1 = *(const float4*)(za1 + ks * 32);
            float4 y1 = *(const float4*)(za1 + ks * 32 + 4);
            Aa0[ks] = pack8(x0, y0);
            Aa1[ks] = pack8(x1, y1);
        }
    }

    __syncthreads();   // phase-0 Bf reads complete before overwrite

    // ---- stage W1 phase 1 (ks 4..7) ----
    if (use_ws) {
        const int4* src = (const int4*)wfrag + 2048;   // 32 KiB offset
        int4*       dst = (int4*)&Bf[0][0][0];
        #pragma unroll
        for (int i = 0; i < 8; ++i)
            dst[tid + i * THREADS] = src[tid + i * THREADS];
    } else {
        __bf16* d = (__bf16*)&Bf[0][0][0];
        for (int idx = tid; idx < H_ * H_; idx += THREADS) {
            int k = idx >> 7, n = idx & 127;
            int ks = k >> 5, gg = (k >> 3) & 3, j = k & 7;
            int nt = n >> 4, ln = (gg << 4) | (n & 15);
            d[ks * 4096 + nt * 512 + ln * 8 + j] = (__bf16)W1[(H_ + k) * H_ + n];
        }
    }
    __syncthreads();

    // ---- phase 1 MFMAs: za @ W1[128:] ----
    #pragma unroll
    for (int nt = 0; nt < 8; ++nt) {
        #pragma unroll
        for (int ks = 0; ks < 4; ++ks) {
            bf16x8 b = Bf[ks][nt][lane];
            acc0[nt] = __builtin_amdgcn_mfma_f32_16x16x32_bf16(Aa0[ks], b, acc0[nt], 0, 0, 0);
            acc1[nt] = __builtin_amdgcn_mfma_f32_16x16x32_bf16(Aa1[ks], b, acc1[nt], 0, 0, 0);
        }
    }

    // ---- epilogue: h = relu(acc + b1); out = h @ W2 + b2 ----
    // C/D layout: channel = nt*16 + m, edge-within-tile = g*4 + reg
    float w2v[8], b1v[8];
    #pragma unroll
    for (int nt = 0; nt < 8; ++nt) {
        int ch = nt * 16 + m;
        w2v[nt] = W2[ch];
        b1v[nt] = b1[ch];
    }
    const float bb = b2[0];

    #pragma unroll
    for (int tile = 0; tile < 2; ++tile) {
        float ps[4];
        #pragma unroll
        for (int r = 0; r < 4; ++r) {
            float s = 0.f;
            #pragma unroll
            for (int nt = 0; nt < 8; ++nt) {
                f32x4 a = tile ? acc1[nt] : acc0[nt];
                float h = a[r] + b1v[nt];
                s = fmaf(fmaxf(h, 0.f), w2v[nt], s);
            }
            ps[r] = s;
        }
        #pragma unroll
        for (int off = 1; off < 16; off <<= 1) {
            #pragma unroll
            for (int r = 0; r < 4; ++r)
                ps[r] += __shfl_xor(ps[r], off, 64);
        }
        if (m == 0) {
            int eb = base + tile * 16 + g * 4;
            if (perm) {
                if (eb + 3 < E) {
                    int4 p = *(const int4*)(perm + eb);
                    out[p.x] = ps[0] + bb;
                    out[p.y] = ps[1] + bb;
                    out[p.z] = ps[2] + bb;
                    out[p.w] = ps[3] + bb;
                } else {
                    #pragma unroll
                    for (int r = 0; r < 4; ++r)
                        if (eb + r < E) out[perm[eb + r]] = ps[r] + bb;
                }
            } else if (eb < E) {
                float4 o = make_float4(ps[0] + bb, ps[1] + bb, ps[2] + bb, ps[3] + bb);
                *(float4*)(out + eb) = o;
            }
        }
    }
}

extern "C" void kernel_launch(void* const* d_in, const int* in_sizes, int n_in,
                              void* d_out, int out_size, void* d_ws, size_t ws_size,
                              hipStream_t stream) {
    const float* z_user  = (const float*)d_in[0];
    const float* z_anime = (const float*)d_in[1];
    const int*   row     = (const int*)d_in[2];
    const int*   col     = (const int*)d_in[3];
    const float* W1      = (const float*)d_in[4];
    const float* b1      = (const float*)d_in[5];
    const float* W2      = (const float*)d_in[6];
    const float* b2      = (const float*)d_in[7];
    float*       out     = (float*)d_out;
    const int E   = in_sizes[2];
    const int nza = in_sizes[1];
    const int nu  = in_sizes[0] / H_;

    const int nb   = (E + EDGES_PER_BLOCK - 1) / EDGES_PER_BLOCK;
    const int Epad = nb * EDGES_PER_BLOCK;

    // workspace layout
    const size_t wfrag_bytes = 2u * H_ * H_ * sizeof(__bf16);           // 64 KiB
    const size_t za_bytes    = (size_t)nza * sizeof(__bf16);
    const size_t hist_bytes  = (size_t)NBUCKET * sizeof(int);
    const size_t idx_bytes   = (size_t)Epad * sizeof(int);
    const size_t need = wfrag_bytes + za_bytes + hist_bytes + 3 * idx_bytes;
    int use_ws = (d_ws != nullptr && ws_size >= need) ? 1 : 0;

    char* p = (char*)d_ws;
    __bf16* wfrag = (__bf16*)p;                 p += wfrag_bytes;
    __bf16* za_bf = (__bf16*)p;                 p += za_bytes;
    int*    hist  = (int*)p;                    p += hist_bytes;
    int*    rowp  = (int*)p;                    p += idx_bytes;
    int*    colp  = (int*)p;                    p += idx_bytes;
    int*    perm  = (int*)p;

    if (use_ws) {
        // bucket shift so (nu >> shift) < NBUCKET
        int shift = 0;
        while ((nu >> shift) >= NBUCKET) shift++;

        hipMemsetAsync(hist, 0, hist_bytes, stream);

        int za_threads = (nza + 7) / 8;
        int nb_prep = 128 + (za_threads + 255) / 256;
        prep_kernel<<<nb_prep, 256, 0, stream>>>(W1, z_anime, wfrag, za_bf, nza);

        int gsb = min(1024, (E + 255) / 256);
        hist_kernel<<<gsb, 256, 0, stream>>>(row, hist, E, shift);
        scan_kernel<<<1, 1024, 0, stream>>>(hist);
        scatter_kernel<<<gsb, 256, 0, stream>>>(row, col, hist, rowp, colp, perm, E, shift);

        edge_decoder_kernel<<<nb, THREADS, 0, stream>>>(
            z_user, z_anime, rowp, colp, perm, W1, b1, W2, b2,
            wfrag, za_bf, 1, out, E);
    } else {
        edge_decoder_kernel<<<nb, THREADS, 0, stream>>>(
            z_user, z_anime, row, col, nullptr, W1, b1, W2, b2,
            wfrag, za_bf, 0, out, E);
    }
}

// Round 4
// 115.490 us; speedup vs baseline: 1.4725x; 1.4725x over previous
//
#include <hip/hip_runtime.h>
#include <hip/hip_bf16.h>
#include <stdint.h>

#define H_ 128
#define THREADS 256
#define EDGES_PER_BLOCK 128   // 4 waves x 32 edges
#define NBUCKET 512
#define NB_SORT 64
#define TS_SORT 1024

typedef __bf16 bf16x8 __attribute__((ext_vector_type(8)));
typedef float  f32x4  __attribute__((ext_vector_type(4)));

// ---------------------------------------------------------------------------
// wfrag layout (bf16 MFMA B-fragment order), idx = ks*4096 + nt*512 + lane*8 + j
//   k = ks*32 + (lane>>4)*8 + j   (K index into [zu|za] concat, 0..255)
//   n = nt*16 + (lane&15)         (output channel, 0..127)
// ---------------------------------------------------------------------------

__device__ inline bf16x8 pack8(float4 a, float4 b) {
    bf16x8 v;
    v[0] = (__bf16)a.x; v[1] = (__bf16)a.y; v[2] = (__bf16)a.z; v[3] = (__bf16)a.w;
    v[4] = (__bf16)b.x; v[5] = (__bf16)b.y; v[6] = (__bf16)b.z; v[7] = (__bf16)b.w;
    return v;
}

// Combined prep: W1 -> bf16 fragment order (first 128 blocks), z_anime -> bf16.
__global__ void prep_kernel(const float* __restrict__ W1,
                            const float* __restrict__ za,
                            __bf16* __restrict__ wfrag,
                            __bf16* __restrict__ za_bf,
                            int nza) {
    int t = blockIdx.x * 256 + threadIdx.x;
    if (t < 32768) {
        int j  = t & 7;
        int ln = (t >> 3) & 63;
        int nt = (t >> 9) & 7;
        int ks = (t >> 12) & 7;
        int k  = ks * 32 + ((ln >> 4) << 3) + j;
        int n  = nt * 16 + (ln & 15);
        wfrag[t] = (__bf16)W1[k * H_ + n];
    } else {
        long i = (long)(t - 32768) * 8;
        if (i < nza) {
            float4 a = *(const float4*)(za + i);
            float4 b = *(const float4*)(za + i + 4);
            *(bf16x8*)(za_bf + i) = pack8(a, b);
        }
    }
}

// ---- near-atomic-free counting sort by row bucket --------------------------
// hist: per-block LDS histogram -> part[p][b]   (no global atomics)
__global__ __launch_bounds__(TS_SORT)
void hist_kernel(const int* __restrict__ row, int* __restrict__ part,
                 int E, int shift) {
    __shared__ int h[NBUCKET];
    const int p = blockIdx.x, tid = threadIdx.x;
    if (tid < NBUCKET) h[tid] = 0;
    __syncthreads();
    const int chunk = (E + NB_SORT - 1) / NB_SORT;
    const int s = p * chunk, e = min(s + chunk, E);
    for (int i = s + tid; i < e; i += TS_SORT)
        atomicAdd(&h[row[i] >> shift], 1);
    __syncthreads();
    if (tid < NBUCKET) part[p * NBUCKET + tid] = h[tid];
}

// scan: one block, NBUCKET threads. part[p][b] -> global slot base for (p,b).
__global__ __launch_bounds__(NBUCKET)
void scan_kernel(int* __restrict__ part) {
    __shared__ int wsum[8];
    const int b = threadIdx.x;
    int s = 0;
    #pragma unroll 4
    for (int p = 0; p < NB_SORT; ++p) s += part[p * NBUCKET + b];

    // exclusive scan of s over 512 threads
    const int lane = b & 63, wv = b >> 6;
    int inc = s;
    #pragma unroll
    for (int off = 1; off < 64; off <<= 1) {
        int t = __shfl_up(inc, off, 64);
        if (lane >= off) inc += t;
    }
    if (lane == 63) wsum[wv] = inc;
    __syncthreads();
    if (wv == 0 && lane < 8) {
        int ws = wsum[lane];
        #pragma unroll
        for (int off = 1; off < 8; off <<= 1) {
            int t = __shfl_up(ws, off, 64);
            if (lane >= off) ws += t;
        }
        wsum[lane] = ws;
    }
    __syncthreads();
    int base = ((wv > 0) ? wsum[wv - 1] : 0) + inc - s;   // exclusive prefix

    int run = base;
    #pragma unroll 4
    for (int p = 0; p < NB_SORT; ++p) {
        int t = part[p * NBUCKET + b];
        part[p * NBUCKET + b] = run;
        run += t;
    }
}

// scatter: LDS cursors from part[p][.], LDS atomics assign slots.
__global__ __launch_bounds__(TS_SORT)
void scatter_kernel(const int* __restrict__ row, const int* __restrict__ col,
                    const int* __restrict__ part,
                    int* __restrict__ rowp, int* __restrict__ colp,
                    int* __restrict__ perm, int E, int shift) {
    __shared__ int pos[NBUCKET];
    const int p = blockIdx.x, tid = threadIdx.x;
    if (tid < NBUCKET) pos[tid] = part[p * NBUCKET + tid];
    __syncthreads();
    const int chunk = (E + NB_SORT - 1) / NB_SORT;
    const int s = p * chunk, e = min(s + chunk, E);
    for (int i = s + tid; i < e; i += TS_SORT) {
        int r = row[i], c = col[i];
        int slot = atomicAdd(&pos[r >> shift], 1);
        rowp[slot] = r;
        colp[slot] = c;
        perm[slot] = i;
    }
}

__global__ __launch_bounds__(THREADS, 3)
void edge_decoder_kernel(const float* __restrict__ z_user,
                         const float* __restrict__ z_anime,
                         const int*   __restrict__ rowp,
                         const int*   __restrict__ colp,
                         const int*   __restrict__ perm,   // null -> direct store
                         const float* __restrict__ W1,
                         const float* __restrict__ b1,
                         const float* __restrict__ W2,
                         const float* __restrict__ b2,
                         const __bf16* __restrict__ wfrag,
                         const __bf16* __restrict__ za_bf,
                         int use_ws,
                         float* __restrict__ out,
                         int E, int nwg) {
    // One K-phase of B fragments: [ks 0..3][nt][lane] of 8 bf16 = 32 KiB
    __shared__ bf16x8 Bf[4][8][64];

    // XCD-chunked bijective swizzle (8 XCDs, round-robin dispatch ->
    // contiguous logical chunk per XCD) so consecutive sorted blocks share L2.
    int wg = blockIdx.x;
    if (use_ws) {
        const int nx = 8;
        int q = nwg / nx, r = nwg % nx;
        int xcd = wg % nx, idx = wg / nx;
        int basewg = (xcd < r) ? xcd * (q + 1) : r * (q + 1) + (xcd - r) * q;
        wg = basewg + idx;
    }

    const int tid  = threadIdx.x;
    const int lane = tid & 63;
    const int wv   = tid >> 6;
    const int g    = lane >> 4;   // k-group within 32-wide K-step
    const int m    = lane & 15;   // edge-within-Mtile (A); channel-within-Ntile (C)
    const int base = wg * EDGES_PER_BLOCK + wv * 32;

    int e0 = base + m;        int e0c = e0 < E ? e0 : 0;
    int e1 = base + 16 + m;   int e1c = e1 < E ? e1 : 0;
    const int r0 = rowp[e0c], c0 = colp[e0c];
    const int r1 = rowp[e1c], c1 = colp[e1c];

    // ---- gather zu (fp32 -> bf16 in registers), phase-0 A operands ----
    bf16x8 Au0[4], Au1[4];
    {
        const float* zu0 = z_user + (size_t)r0 * H_ + g * 8;
        const float* zu1 = z_user + (size_t)r1 * H_ + g * 8;
        #pragma unroll
        for (int ks = 0; ks < 4; ++ks) {
            float4 x0 = *(const float4*)(zu0 + ks * 32);
            float4 y0 = *(const float4*)(zu0 + ks * 32 + 4);
            float4 x1 = *(const float4*)(zu1 + ks * 32);
            float4 y1 = *(const float4*)(zu1 + ks * 32 + 4);
            Au0[ks] = pack8(x0, y0);
            Au1[ks] = pack8(x1, y1);
        }
    }

    // ---- stage W1 phase 0 (ks 0..3) ----
    if (use_ws) {
        const int4* src = (const int4*)wfrag;       // phase 0 at offset 0
        int4*       dst = (int4*)&Bf[0][0][0];
        #pragma unroll
        for (int i = 0; i < 8; ++i)
            dst[tid + i * THREADS] = src[tid + i * THREADS];
    } else {
        __bf16* d = (__bf16*)&Bf[0][0][0];
        for (int idx = tid; idx < H_ * H_; idx += THREADS) {
            int k = idx >> 7, n = idx & 127;
            int ks = k >> 5, gg = (k >> 3) & 3, j = k & 7;
            int nt = n >> 4, ln = (gg << 4) | (n & 15);
            d[ks * 4096 + nt * 512 + ln * 8 + j] = (__bf16)W1[k * H_ + n];
        }
    }
    __syncthreads();

    f32x4 acc0[8], acc1[8];
    #pragma unroll
    for (int nt = 0; nt < 8; ++nt) {
        acc0[nt] = (f32x4){0.f, 0.f, 0.f, 0.f};
        acc1[nt] = (f32x4){0.f, 0.f, 0.f, 0.f};
    }

    // ---- phase 0 MFMAs: zu @ W1[:128] ----
    #pragma unroll
    for (int nt = 0; nt < 8; ++nt) {
        #pragma unroll
        for (int ks = 0; ks < 4; ++ks) {
            bf16x8 b = Bf[ks][nt][lane];
            acc0[nt] = __builtin_amdgcn_mfma_f32_16x16x32_bf16(Au0[ks], b, acc0[nt], 0, 0, 0);
            acc1[nt] = __builtin_amdgcn_mfma_f32_16x16x32_bf16(Au1[ks], b, acc1[nt], 0, 0, 0);
        }
    }

    // ---- issue za loads (overlap with barrier + phase-1 staging) ----
    bf16x8 Aa0[4], Aa1[4];
    if (use_ws) {
        const __bf16* za0 = za_bf + (size_t)c0 * H_ + g * 8;
        const __bf16* za1 = za_bf + (size_t)c1 * H_ + g * 8;
        #pragma unroll
        for (int ks = 0; ks < 4; ++ks) {
            Aa0[ks] = *(const bf16x8*)(za0 + ks * 32);
            Aa1[ks] = *(const bf16x8*)(za1 + ks * 32);
        }
    } else {
        const float* za0 = z_anime + (size_t)c0 * H_ + g * 8;
        const float* za1 = z_anime + (size_t)c1 * H_ + g * 8;
        #pragma unroll
        for (int ks = 0; ks < 4; ++ks) {
            float4 x0 = *(const float4*)(za0 + ks * 32);
            float4 y0 = *(const float4*)(za0 + ks * 32 + 4);
            float4 x1 = *(const float4*)(za1 + ks * 32);
            float4 y1 = *(const float4*)(za1 + ks * 32 + 4);
            Aa0[ks] = pack8(x0, y0);
            Aa1[ks] = pack8(x1, y1);
        }
    }

    __syncthreads();   // phase-0 Bf reads complete before overwrite

    // ---- stage W1 phase 1 (ks 4..7) ----
    if (use_ws) {
        const int4* src = (const int4*)wfrag + 2048;   // 32 KiB offset
        int4*       dst = (int4*)&Bf[0][0][0];
        #pragma unroll
        for (int i = 0; i < 8; ++i)
            dst[tid + i * THREADS] = src[tid + i * THREADS];
    } else {
        __bf16* d = (__bf16*)&Bf[0][0][0];
        for (int idx = tid; idx < H_ * H_; idx += THREADS) {
            int k = idx >> 7, n = idx & 127;
            int ks = k >> 5, gg = (k >> 3) & 3, j = k & 7;
            int nt = n >> 4, ln = (gg << 4) | (n & 15);
            d[ks * 4096 + nt * 512 + ln * 8 + j] = (__bf16)W1[(H_ + k) * H_ + n];
        }
    }
    __syncthreads();

    // ---- phase 1 MFMAs: za @ W1[128:] ----
    #pragma unroll
    for (int nt = 0; nt < 8; ++nt) {
        #pragma unroll
        for (int ks = 0; ks < 4; ++ks) {
            bf16x8 b = Bf[ks][nt][lane];
            acc0[nt] = __builtin_amdgcn_mfma_f32_16x16x32_bf16(Aa0[ks], b, acc0[nt], 0, 0, 0);
            acc1[nt] = __builtin_amdgcn_mfma_f32_16x16x32_bf16(Aa1[ks], b, acc1[nt], 0, 0, 0);
        }
    }

    // ---- epilogue: h = relu(acc + b1); out = h @ W2 + b2 ----
    // C/D layout: channel = nt*16 + m, edge-within-tile = g*4 + reg
    float w2v[8], b1v[8];
    #pragma unroll
    for (int nt = 0; nt < 8; ++nt) {
        int ch = nt * 16 + m;
        w2v[nt] = W2[ch];
        b1v[nt] = b1[ch];
    }
    const float bb = b2[0];

    #pragma unroll
    for (int tile = 0; tile < 2; ++tile) {
        float ps[4];
        #pragma unroll
        for (int r = 0; r < 4; ++r) {
            float s = 0.f;
            #pragma unroll
            for (int nt = 0; nt < 8; ++nt) {
                f32x4 a = tile ? acc1[nt] : acc0[nt];
                float h = a[r] + b1v[nt];
                s = fmaf(fmaxf(h, 0.f), w2v[nt], s);
            }
            ps[r] = s;
        }
        #pragma unroll
        for (int off = 1; off < 16; off <<= 1) {
            #pragma unroll
            for (int r = 0; r < 4; ++r)
                ps[r] += __shfl_xor(ps[r], off, 64);
        }
        if (m == 0) {
            int eb = base + tile * 16 + g * 4;
            if (perm) {
                if (eb + 3 < E) {
                    int4 p = *(const int4*)(perm + eb);
                    out[p.x] = ps[0] + bb;
                    out[p.y] = ps[1] + bb;
                    out[p.z] = ps[2] + bb;
                    out[p.w] = ps[3] + bb;
                } else {
                    #pragma unroll
                    for (int r = 0; r < 4; ++r)
                        if (eb + r < E) out[perm[eb + r]] = ps[r] + bb;
                }
            } else if (eb < E) {
                float4 o = make_float4(ps[0] + bb, ps[1] + bb, ps[2] + bb, ps[3] + bb);
                *(float4*)(out + eb) = o;
            }
        }
    }
}

extern "C" void kernel_launch(void* const* d_in, const int* in_sizes, int n_in,
                              void* d_out, int out_size, void* d_ws, size_t ws_size,
                              hipStream_t stream) {
    const float* z_user  = (const float*)d_in[0];
    const float* z_anime = (const float*)d_in[1];
    const int*   row     = (const int*)d_in[2];
    const int*   col     = (const int*)d_in[3];
    const float* W1      = (const float*)d_in[4];
    const float* b1      = (const float*)d_in[5];
    const float* W2      = (const float*)d_in[6];
    const float* b2      = (const float*)d_in[7];
    float*       out     = (float*)d_out;
    const int E   = in_sizes[2];
    const int nza = in_sizes[1];
    const int nu  = in_sizes[0] / H_;

    const int nb   = (E + EDGES_PER_BLOCK - 1) / EDGES_PER_BLOCK;
    const int Epad = nb * EDGES_PER_BLOCK;

    // workspace layout
    const size_t wfrag_bytes = 2u * H_ * H_ * sizeof(__bf16);           // 64 KiB
    const size_t za_bytes    = ((size_t)nza * sizeof(__bf16) + 255) & ~255ull;
    const size_t part_bytes  = (size_t)NB_SORT * NBUCKET * sizeof(int); // 128 KiB
    const size_t idx_bytes   = (size_t)Epad * sizeof(int);
    const size_t need = wfrag_bytes + za_bytes + part_bytes + 3 * idx_bytes;
    int use_ws = (d_ws != nullptr && ws_size >= need) ? 1 : 0;

    char* p = (char*)d_ws;
    __bf16* wfrag = (__bf16*)p;                 p += wfrag_bytes;
    __bf16* za_bf = (__bf16*)p;                 p += za_bytes;
    int*    part  = (int*)p;                    p += part_bytes;
    int*    rowp  = (int*)p;                    p += idx_bytes;
    int*    colp  = (int*)p;                    p += idx_bytes;
    int*    perm  = (int*)p;

    if (use_ws) {
        // bucket shift so (nu >> shift) < NBUCKET
        int shift = 0;
        while ((nu >> shift) >= NBUCKET) shift++;

        int za_threads = (nza + 7) / 8;
        int nb_prep = 128 + (za_threads + 255) / 256;
        prep_kernel<<<nb_prep, 256, 0, stream>>>(W1, z_anime, wfrag, za_bf, nza);

        hist_kernel<<<NB_SORT, TS_SORT, 0, stream>>>(row, part, E, shift);
        scan_kernel<<<1, NBUCKET, 0, stream>>>(part);
        scatter_kernel<<<NB_SORT, TS_SORT, 0, stream>>>(row, col, part,
                                                        rowp, colp, perm, E, shift);

        edge_decoder_kernel<<<nb, THREADS, 0, stream>>>(
            z_user, z_anime, rowp, colp, perm, W1, b1, W2, b2,
            wfrag, za_bf, 1, out, E, nb);
    } else {
        edge_decoder_kernel<<<nb, THREADS, 0, stream>>>(
            z_user, z_anime, row, col, nullptr, W1, b1, W2, b2,
            wfrag, za_bf, 0, out, E, nb);
    }
}

// Round 5
// 106.043 us; speedup vs baseline: 1.6037x; 1.0891x over previous
//
#include <hip/hip_runtime.h>
#include <hip/hip_bf16.h>
#include <stdint.h>

#define H_ 128
#define NW 3                       // waves per block
#define THREADS (NW * 64)
#define TILE_E 32                  // edges per wave-tile
#define NBLOCKS 256

typedef __bf16 bf16x8 __attribute__((ext_vector_type(8)));
typedef float  f32x4  __attribute__((ext_vector_type(4)));

// wfrag layout (bf16 MFMA B-fragment order), idx = ks*4096 + nt*512 + lane*8 + j
//   k = ks*32 + (lane>>4)*8 + j   (K index into [zu|za] concat, 0..255)
//   n = nt*16 + (lane&15)         (output channel, 0..127)

__device__ inline bf16x8 pack8(float4 a, float4 b) {
    bf16x8 v;
    v[0] = (__bf16)a.x; v[1] = (__bf16)a.y; v[2] = (__bf16)a.z; v[3] = (__bf16)a.w;
    v[4] = (__bf16)b.x; v[5] = (__bf16)b.y; v[6] = (__bf16)b.z; v[7] = (__bf16)b.w;
    return v;
}

// prep: W1 -> bf16 fragment order (first 128 blocks), z_anime -> bf16.
__global__ void prep_kernel(const float* __restrict__ W1,
                            const float* __restrict__ za,
                            __bf16* __restrict__ wfrag,
                            __bf16* __restrict__ za_bf,
                            int nza) {
    int t = blockIdx.x * 256 + threadIdx.x;
    if (t < 32768) {
        int j  = t & 7;
        int ln = (t >> 3) & 63;
        int nt = (t >> 9) & 7;
        int ks = (t >> 12) & 7;
        int k  = ks * 32 + ((ln >> 4) << 3) + j;
        int n  = nt * 16 + (ln & 15);
        wfrag[t] = (__bf16)W1[k * H_ + n];
    } else {
        long i = (long)(t - 32768) * 8;
        if (i < nza) {
            float4 a = *(const float4*)(za + i);
            float4 b = *(const float4*)(za + i + 4);
            *(bf16x8*)(za_bf + i) = pack8(a, b);
        }
    }
}

// async global->LDS, 16B per lane, lds dest = uniform base + lane*16
#define GLD16(gp, lp) __builtin_amdgcn_global_load_lds(                      \
    (const __attribute__((address_space(1))) void*)(gp),                     \
    (__attribute__((address_space(3))) void*)(lp), 16, 0, 0)

__global__ __launch_bounds__(THREADS, 1)
void edge_decoder_kernel(const float* __restrict__ z_user,
                         const float* __restrict__ z_anime,
                         const int*   __restrict__ row,
                         const int*   __restrict__ col,
                         const float* __restrict__ W1,
                         const float* __restrict__ b1,
                         const float* __restrict__ W2,
                         const float* __restrict__ b2,
                         const __bf16* __restrict__ wfrag,
                         const __bf16* __restrict__ za_bf,
                         int use_ws,
                         float* __restrict__ out,
                         int E) {
    __shared__ bf16x8 Bf[8][8][64];            // 64 KiB: full W1 fragments
    __shared__ float  ZU[NW][2][TILE_E * H_];  // 96 KiB: per-wave dbuf zu tiles

    const int tid  = threadIdx.x;
    const int lane = tid & 63;
    const int wv   = tid >> 6;
    const int g    = lane >> 4;
    const int m    = lane & 15;

    // ---- stage W1 once ----
    if (use_ws) {
        const int4* src = (const int4*)wfrag;
        int4*       dst = (int4*)&Bf[0][0][0];
        for (int i = tid; i < 4096; i += THREADS) dst[i] = src[i];
    } else {
        __bf16* d = (__bf16*)&Bf[0][0][0];
        for (int idx = tid; idx < 2 * H_ * H_; idx += THREADS) {
            int k = idx >> 7, n = idx & 127;
            int ks = k >> 5, gg = (k >> 3) & 3, j = k & 7;
            int nt = n >> 4, ln = (gg << 4) | (n & 15);
            d[ks * 4096 + nt * 512 + ln * 8 + j] = (__bf16)W1[k * H_ + n];
        }
    }
    __syncthreads();

    float w2v[8], b1v[8];
    #pragma unroll
    for (int nt = 0; nt < 8; ++nt) { int ch = nt * 16 + m; w2v[nt] = W2[ch]; b1v[nt] = b1[ch]; }
    const float bb = b2[0];

    const int T = (E + TILE_E - 1) / TILE_E;
    const int NSTREAM = gridDim.x * NW;
    int t = blockIdx.x * NW + wv;
    if (t >= T) return;

    float* zbuf0 = &ZU[wv][0][0];
    float* zbuf1 = &ZU[wv][1][0];

    // ---- prologue: indices + DMA for tile t, indices for t+1 ----
    int tb = t * TILE_E;
    int ei = tb + (lane & 31); if (ei >= E) ei = E - 1;
    int rv = row[ei];
    int e0 = tb + m;      if (e0 >= E) e0 = E - 1;
    int e1 = tb + 16 + m; if (e1 >= E) e1 = E - 1;
    int ca0 = col[e0], ca1 = col[e1];

    {
        #pragma unroll
        for (int i = 0; i < 16; ++i) {
            int r0 = __builtin_amdgcn_readlane(rv, 2 * i);
            int r1 = __builtin_amdgcn_readlane(rv, 2 * i + 1);
            int r  = (lane < 32) ? r0 : r1;
            int e  = 2 * i + (lane >> 5);
            int c  = (lane & 31) ^ (e & 7);
            GLD16(z_user + (size_t)r * H_ + c * 4, zbuf0 + i * 256);
        }
    }

    int t1 = t + NSTREAM;
    int tbn = (t1 < T ? t1 : 0) * TILE_E;
    int en = tbn + (lane & 31); if (en >= E) en = E - 1;
    int rv1 = row[en];
    int f0 = tbn + m;      if (f0 >= E) f0 = E - 1;
    int f1 = tbn + 16 + m; if (f1 >= E) f1 = E - 1;
    int cb0 = col[f0], cb1 = col[f1];

    int cur = 0;
    while (true) {
        // drain: tile t's DMA + this iter's address regs are now resident
        asm volatile("s_waitcnt vmcnt(0)" ::: "memory");

        const int nxt = t + NSTREAM;
        const bool have_next = (nxt < T);
        float* zb  = cur ? zbuf1 : zbuf0;
        float* zbn = cur ? zbuf0 : zbuf1;

        // 1) za fragment loads (oldest in this iter's vmem window)
        bf16x8 Aa0[4], Aa1[4];
        if (use_ws) {
            const __bf16* p0 = za_bf + (size_t)ca0 * H_ + g * 8;
            const __bf16* p1 = za_bf + (size_t)ca1 * H_ + g * 8;
            #pragma unroll
            for (int ks = 0; ks < 4; ++ks) {
                Aa0[ks] = *(const bf16x8*)(p0 + ks * 32);
                Aa1[ks] = *(const bf16x8*)(p1 + ks * 32);
            }
        } else {
            const float* p0 = z_anime + (size_t)ca0 * H_ + g * 8;
            const float* p1 = z_anime + (size_t)ca1 * H_ + g * 8;
            #pragma unroll
            for (int ks = 0; ks < 4; ++ks) {
                Aa0[ks] = pack8(*(const float4*)(p0 + ks * 32), *(const float4*)(p0 + ks * 32 + 4));
                Aa1[ks] = pack8(*(const float4*)(p1 + ks * 32), *(const float4*)(p1 + ks * 32 + 4));
            }
        }

        // 2) zu A-frags from LDS (XOR-swizzled chunks), BEFORE issuing next DMA
        //    so any conservative auto-vmcnt here cannot drain the new pipeline
        bf16x8 Au0[4], Au1[4];
        {
            const int swz = m & 7;
            const float* r0p = zb + m * H_;
            const float* r1p = zb + (m + 16) * H_;
            #pragma unroll
            for (int ks = 0; ks < 4; ++ks) {
                int c0 = g * 2 + ks * 8;
                float4 x0 = *(const float4*)(r0p + (((c0    ) ^ swz) << 2));
                float4 y0 = *(const float4*)(r0p + (((c0 + 1) ^ swz) << 2));
                float4 x1 = *(const float4*)(r1p + (((c0    ) ^ swz) << 2));
                float4 y1 = *(const float4*)(r1p + (((c0 + 1) ^ swz) << 2));
                Au0[ks] = pack8(x0, y0);
                Au1[ks] = pack8(x1, y1);
            }
        }

        // 3) issue DMA for tile t+1 (stays in flight through all MFMAs below)
        if (have_next) {
            #pragma unroll
            for (int i = 0; i < 16; ++i) {
                int r0 = __builtin_amdgcn_readlane(rv1, 2 * i);
                int r1 = __builtin_amdgcn_readlane(rv1, 2 * i + 1);
                int r  = (lane < 32) ? r0 : r1;
                int e  = 2 * i + (lane >> 5);
                int c  = (lane & 31) ^ (e & 7);
                GLD16(z_user + (size_t)r * H_ + c * 4, zbn + i * 256);
            }
        }

        // 4) prefetch indices for t+2
        int t2 = t + 2 * NSTREAM;
        int tb2 = (t2 < T ? t2 : 0) * TILE_E;
        int e2 = tb2 + (lane & 31); if (e2 >= E) e2 = E - 1;
        int rv2 = row[e2];
        int h0 = tb2 + m;      if (h0 >= E) h0 = E - 1;
        int h1 = tb2 + 16 + m; if (h1 >= E) h1 = E - 1;
        int cc0 = col[h0], cc1 = col[h1];

        // 5) MFMAs: zu half (K 0..127) then za half (K 128..255)
        f32x4 acc0[8], acc1[8];
        #pragma unroll
        for (int nt = 0; nt < 8; ++nt) {
            acc0[nt] = (f32x4){0.f, 0.f, 0.f, 0.f};
            acc1[nt] = (f32x4){0.f, 0.f, 0.f, 0.f};
        }
        #pragma unroll
        for (int nt = 0; nt < 8; ++nt) {
            #pragma unroll
            for (int ks = 0; ks < 4; ++ks) {
                bf16x8 b = Bf[ks][nt][lane];
                acc0[nt] = __builtin_amdgcn_mfma_f32_16x16x32_bf16(Au0[ks], b, acc0[nt], 0, 0, 0);
                acc1[nt] = __builtin_amdgcn_mfma_f32_16x16x32_bf16(Au1[ks], b, acc1[nt], 0, 0, 0);
            }
        }
        #pragma unroll
        for (int nt = 0; nt < 8; ++nt) {
            #pragma unroll
            for (int ks = 0; ks < 4; ++ks) {
                bf16x8 b = Bf[4 + ks][nt][lane];
                acc0[nt] = __builtin_amdgcn_mfma_f32_16x16x32_bf16(Aa0[ks], b, acc0[nt], 0, 0, 0);
                acc1[nt] = __builtin_amdgcn_mfma_f32_16x16x32_bf16(Aa1[ks], b, acc1[nt], 0, 0, 0);
            }
        }

        // 6) epilogue: relu(acc+b1) @ W2 + b2, 16-lane reduce, store
        int tb0 = t * TILE_E;
        #pragma unroll
        for (int tile = 0; tile < 2; ++tile) {
            float ps[4];
            #pragma unroll
            for (int r = 0; r < 4; ++r) {
                float s = 0.f;
                #pragma unroll
                for (int nt = 0; nt < 8; ++nt) {
                    f32x4 a = tile ? acc1[nt] : acc0[nt];
                    float h = a[r] + b1v[nt];
                    s = fmaf(fmaxf(h, 0.f), w2v[nt], s);
                }
                ps[r] = s;
            }
            #pragma unroll
            for (int off = 1; off < 16; off <<= 1) {
                #pragma unroll
                for (int r = 0; r < 4; ++r)
                    ps[r] += __shfl_xor(ps[r], off, 64);
            }
            if (m == 0) {
                int eb = tb0 + tile * 16 + g * 4;
                if (eb + 3 < E) {
                    float4 o = make_float4(ps[0] + bb, ps[1] + bb, ps[2] + bb, ps[3] + bb);
                    *(float4*)(out + eb) = o;
                } else {
                    #pragma unroll
                    for (int r = 0; r < 4; ++r)
                        if (eb + r < E) out[eb + r] = ps[r] + bb;
                }
            }
        }

        if (!have_next) break;
        t = nxt; cur ^= 1;
        rv1 = rv2;
        ca0 = cb0; ca1 = cb1;
        cb0 = cc0; cb1 = cc1;
    }
}

extern "C" void kernel_launch(void* const* d_in, const int* in_sizes, int n_in,
                              void* d_out, int out_size, void* d_ws, size_t ws_size,
                              hipStream_t stream) {
    const float* z_user  = (const float*)d_in[0];
    const float* z_anime = (const float*)d_in[1];
    const int*   row     = (const int*)d_in[2];
    const int*   col     = (const int*)d_in[3];
    const float* W1      = (const float*)d_in[4];
    const float* b1      = (const float*)d_in[5];
    const float* W2      = (const float*)d_in[6];
    const float* b2      = (const float*)d_in[7];
    float*       out     = (float*)d_out;
    const int E   = in_sizes[2];
    const int nza = in_sizes[1];

    const size_t wfrag_bytes = 2u * H_ * H_ * sizeof(__bf16);   // 64 KiB
    const size_t need = wfrag_bytes + (size_t)nza * sizeof(__bf16);
    int use_ws = (d_ws != nullptr && ws_size >= need) ? 1 : 0;

    __bf16* wfrag = (__bf16*)d_ws;
    __bf16* za_bf = (__bf16*)((char*)d_ws + wfrag_bytes);

    if (use_ws) {
        int za_threads = (nza + 7) / 8;
        int nb_prep = 128 + (za_threads + 255) / 256;
        prep_kernel<<<nb_prep, 256, 0, stream>>>(W1, z_anime, wfrag, za_bf, nza);
    }

    edge_decoder_kernel<<<NBLOCKS, THREADS, 0, stream>>>(
        z_user, z_anime, row, col, W1, b1, W2, b2,
        wfrag, za_bf, use_ws, out, E);
}

// Round 6
// 78.229 us; speedup vs baseline: 2.1738x; 1.3555x over previous
//
#include <hip/hip_runtime.h>
#include <hip/hip_bf16.h>
#include <stdint.h>

#define H_ 128
#define THREADS 256
#define EPB 64            // edges per block: 4 waves x 16

typedef __bf16 bf16x8 __attribute__((ext_vector_type(8)));
typedef float  f32x4  __attribute__((ext_vector_type(4)));

// wfrag layout (bf16 MFMA B-fragment order), idx = ks*4096 + nt*512 + lane*8 + j
//   k = ks*32 + (lane>>4)*8 + j   (K index into [zu|za] concat, 0..255)
//   n = nt*16 + (lane&15)         (output channel, 0..127)

__device__ inline bf16x8 pack8(float4 a, float4 b) {
    bf16x8 v;
    v[0] = (__bf16)a.x; v[1] = (__bf16)a.y; v[2] = (__bf16)a.z; v[3] = (__bf16)a.w;
    v[4] = (__bf16)b.x; v[5] = (__bf16)b.y; v[6] = (__bf16)b.z; v[7] = (__bf16)b.w;
    return v;
}

// prep: W1 -> bf16 fragment order (first 128 blocks), z_anime -> bf16.
__global__ void prep_kernel(const float* __restrict__ W1,
                            const float* __restrict__ za,
                            __bf16* __restrict__ wfrag,
                            __bf16* __restrict__ za_bf,
                            int nza) {
    int t = blockIdx.x * 256 + threadIdx.x;
    if (t < 32768) {
        int j  = t & 7;
        int ln = (t >> 3) & 63;
        int nt = (t >> 9) & 7;
        int ks = (t >> 12) & 7;
        int k  = ks * 32 + ((ln >> 4) << 3) + j;
        int n  = nt * 16 + (ln & 15);
        wfrag[t] = (__bf16)W1[k * H_ + n];
    } else {
        long i = (long)(t - 32768) * 8;
        if (i < nza) {
            float4 a = *(const float4*)(za + i);
            float4 b = *(const float4*)(za + i + 4);
            *(bf16x8*)(za_bf + i) = pack8(a, b);
        }
    }
}

__global__ __launch_bounds__(THREADS, 4)
void edge_decoder_kernel(const float* __restrict__ z_user,
                         const float* __restrict__ z_anime,
                         const int*   __restrict__ row,
                         const int*   __restrict__ col,
                         const float* __restrict__ W1,
                         const float* __restrict__ b1,
                         const float* __restrict__ W2,
                         const float* __restrict__ b2,
                         const __bf16* __restrict__ wfrag,
                         const __bf16* __restrict__ za_bf,
                         int use_ws,
                         float* __restrict__ out,
                         int E) {
    // One K-phase of B fragments: [ks 0..3][nt][lane] of 8 bf16 = 32 KiB
    __shared__ bf16x8 Bf[4][8][64];

    const int tid  = threadIdx.x;
    const int lane = tid & 63;
    const int wv   = tid >> 6;
    const int g    = lane >> 4;   // k-group within 32-wide K-step
    const int m    = lane & 15;   // edge-within-Mtile (A); channel-within-Ntile (C)
    const int base = blockIdx.x * EPB + wv * 16;

    int e = base + m; if (e >= E) e = E - 1;
    const int r0 = row[e], c0 = col[e];

    // ---- issue ALL gathers up front: zu (fp32) + za (bf16 if prepped) ----
    float4 xu[8];
    {
        const float* zu = z_user + (size_t)r0 * H_ + g * 8;
        #pragma unroll
        for (int ks = 0; ks < 4; ++ks) {
            xu[2 * ks]     = *(const float4*)(zu + ks * 32);
            xu[2 * ks + 1] = *(const float4*)(zu + ks * 32 + 4);
        }
    }
    bf16x8 Aa[4];
    if (use_ws) {
        const __bf16* za = za_bf + (size_t)c0 * H_ + g * 8;
        #pragma unroll
        for (int ks = 0; ks < 4; ++ks)
            Aa[ks] = *(const bf16x8*)(za + ks * 32);
    }

    float w2v[8], b1v[8];
    #pragma unroll
    for (int nt = 0; nt < 8; ++nt) { int ch = nt * 16 + m; w2v[nt] = W2[ch]; b1v[nt] = b1[ch]; }
    const float bb = b2[0];

    // ---- stage W1 phase 0 (ks 0..3) ----
    if (use_ws) {
        const int4* src = (const int4*)wfrag;
        int4*       dst = (int4*)&Bf[0][0][0];
        #pragma unroll
        for (int i = 0; i < 8; ++i)
            dst[tid + i * THREADS] = src[tid + i * THREADS];
    } else {
        __bf16* d = (__bf16*)&Bf[0][0][0];
        for (int idx = tid; idx < H_ * H_; idx += THREADS) {
            int k = idx >> 7, n = idx & 127;
            int ks = k >> 5, gg = (k >> 3) & 3, j = k & 7;
            int nt = n >> 4, ln = (gg << 4) | (n & 15);
            d[ks * 4096 + nt * 512 + ln * 8 + j] = (__bf16)W1[k * H_ + n];
        }
    }
    __syncthreads();

    // pack zu -> A fragments (xu dies here)
    bf16x8 Au[4];
    #pragma unroll
    for (int ks = 0; ks < 4; ++ks)
        Au[ks] = pack8(xu[2 * ks], xu[2 * ks + 1]);

    f32x4 acc[8];
    #pragma unroll
    for (int nt = 0; nt < 8; ++nt) acc[nt] = (f32x4){0.f, 0.f, 0.f, 0.f};

    // ---- phase 0 MFMAs: zu @ W1[:128] ----
    #pragma unroll
    for (int nt = 0; nt < 8; ++nt) {
        #pragma unroll
        for (int ks = 0; ks < 4; ++ks) {
            bf16x8 b = Bf[ks][nt][lane];
            acc[nt] = __builtin_amdgcn_mfma_f32_16x16x32_bf16(Au[ks], b, acc[nt], 0, 0, 0);
        }
    }

    // fallback za path (fp32 load + pack) only when no workspace
    if (!use_ws) {
        const float* za = z_anime + (size_t)c0 * H_ + g * 8;
        #pragma unroll
        for (int ks = 0; ks < 4; ++ks)
            Aa[ks] = pack8(*(const float4*)(za + ks * 32),
                           *(const float4*)(za + ks * 32 + 4));
    }

    __syncthreads();   // phase-0 Bf reads complete before overwrite

    // ---- stage W1 phase 1 (ks 4..7) ----
    if (use_ws) {
        const int4* src = (const int4*)wfrag + 2048;   // 32 KiB offset
        int4*       dst = (int4*)&Bf[0][0][0];
        #pragma unroll
        for (int i = 0; i < 8; ++i)
            dst[tid + i * THREADS] = src[tid + i * THREADS];
    } else {
        __bf16* d = (__bf16*)&Bf[0][0][0];
        for (int idx = tid; idx < H_ * H_; idx += THREADS) {
            int k = idx >> 7, n = idx & 127;
            int ks = k >> 5, gg = (k >> 3) & 3, j = k & 7;
            int nt = n >> 4, ln = (gg << 4) | (n & 15);
            d[ks * 4096 + nt * 512 + ln * 8 + j] = (__bf16)W1[(H_ + k) * H_ + n];
        }
    }
    __syncthreads();

    // ---- phase 1 MFMAs: za @ W1[128:] ----
    #pragma unroll
    for (int nt = 0; nt < 8; ++nt) {
        #pragma unroll
        for (int ks = 0; ks < 4; ++ks) {
            bf16x8 b = Bf[ks][nt][lane];
            acc[nt] = __builtin_amdgcn_mfma_f32_16x16x32_bf16(Aa[ks], b, acc[nt], 0, 0, 0);
        }
    }

    // ---- epilogue: h = relu(acc + b1); out = h @ W2 + b2 ----
    // C/D layout: channel = nt*16 + m, edge-within-tile = g*4 + reg
    float ps[4];
    #pragma unroll
    for (int r = 0; r < 4; ++r) {
        float s = 0.f;
        #pragma unroll
        for (int nt = 0; nt < 8; ++nt) {
            float h = acc[nt][r] + b1v[nt];
            s = fmaf(fmaxf(h, 0.f), w2v[nt], s);
        }
        ps[r] = s;
    }
    #pragma unroll
    for (int off = 1; off < 16; off <<= 1) {
        #pragma unroll
        for (int r = 0; r < 4; ++r)
            ps[r] += __shfl_xor(ps[r], off, 64);
    }
    if (m == 0) {
        int eb = base + g * 4;
        if (eb + 3 < E) {
            float4 o = make_float4(ps[0] + bb, ps[1] + bb, ps[2] + bb, ps[3] + bb);
            *(float4*)(out + eb) = o;
        } else {
            #pragma unroll
            for (int r = 0; r < 4; ++r)
                if (eb + r < E) out[eb + r] = ps[r] + bb;
        }
    }
}

extern "C" void kernel_launch(void* const* d_in, const int* in_sizes, int n_in,
                              void* d_out, int out_size, void* d_ws, size_t ws_size,
                              hipStream_t stream) {
    const float* z_user  = (const float*)d_in[0];
    const float* z_anime = (const float*)d_in[1];
    const int*   row     = (const int*)d_in[2];
    const int*   col     = (const int*)d_in[3];
    const float* W1      = (const float*)d_in[4];
    const float* b1      = (const float*)d_in[5];
    const float* W2      = (const float*)d_in[6];
    const float* b2      = (const float*)d_in[7];
    float*       out     = (float*)d_out;
    const int E   = in_sizes[2];
    const int nza = in_sizes[1];

    const size_t wfrag_bytes = 2u * H_ * H_ * sizeof(__bf16);   // 64 KiB
    const size_t need = wfrag_bytes + (size_t)nza * sizeof(__bf16);
    int use_ws = (d_ws != nullptr && ws_size >= need) ? 1 : 0;

    __bf16* wfrag = (__bf16*)d_ws;
    __bf16* za_bf = (__bf16*)((char*)d_ws + wfrag_bytes);

    if (use_ws) {
        int za_threads = (nza + 7) / 8;
        int nb_prep = 128 + (za_threads + 255) / 256;
        prep_kernel<<<nb_prep, 256, 0, stream>>>(W1, z_anime, wfrag, za_bf, nza);
    }

    int nb = (E + EPB - 1) / EPB;
    edge_decoder_kernel<<<nb, THREADS, 0, stream>>>(
        z_user, z_anime, row, col, W1, b1, W2, b2,
        wfrag, za_bf, use_ws, out, E);
}